// Round 4
// baseline (240.408 us; speedup 1.0000x reference)
//
#include <hip/hip_runtime.h>

// Causal depthwise conv1d: y[b,s,h] = sum_j x[b, s-(K-1)+j, h] * w[h,j], * mask[b,s]
// B=4, S=4096, H=2048, K=4, fp32.
// R3->R4: (a) manual 8-deep load batching — R3's VGPR=40 proved the compiler
// serialized loads (shallow MLP) despite unroll; (b) nontemporal stores for y
// so x (134MB) stays fully L3-resident (x+y=268MB exactly thrashed the 256MB L3).

typedef float f4_t __attribute__((ext_vector_type(4)));

constexpr int B_    = 4;
constexpr int S_    = 4096;
constexpr int H_    = 2048;
constexpr int T_    = 32;        // s-positions per block chunk
constexpr int BATCH = 8;         // independent loads in flight per wave
constexpr int H4_   = H_ / 4;    // 512 float4 channel-groups per (b,s) row
constexpr int TPB   = 256;

__global__ __launch_bounds__(TPB) void budgie_dwconv1d_kernel(
    const float* __restrict__ x,     // [B,S,H]
    const float* __restrict__ w,     // [H,K]
    const float* __restrict__ mask,  // [B,S]
    float* __restrict__ y)           // [B,S,H]
{
    const int h4 = blockIdx.x * TPB + threadIdx.x;   // 0..H4_-1
    const int s0 = blockIdx.y * T_;
    const int b  = blockIdx.z;

    const f4_t* __restrict__ x4 = (const f4_t*)x;
    const f4_t* __restrict__ w4 = (const f4_t*)w;
    f4_t* __restrict__ y4 = (f4_t*)y;

    // Per-channel taps: w[h, 0..3] contiguous -> one float4 per channel.
    const int hbase = h4 * 4;
    const f4_t w0 = w4[hbase + 0];
    const f4_t w1 = w4[hbase + 1];
    const f4_t w2 = w4[hbase + 2];
    const f4_t w3 = w4[hbase + 3];

    const long base = (long)b * S_ * H4_ + h4;

    const f4_t zero4 = (f4_t){0.f, 0.f, 0.f, 0.f};
    f4_t xm3 = (s0 >= 3) ? x4[base + (long)(s0 - 3) * H4_] : zero4;
    f4_t xm2 = (s0 >= 2) ? x4[base + (long)(s0 - 2) * H4_] : zero4;
    f4_t xm1 = (s0 >= 1) ? x4[base + (long)(s0 - 1) * H4_] : zero4;

    for (int c = 0; c < T_ / BATCH; ++c) {
        const int sc = s0 + c * BATCH;

        // Phase 1: issue all BATCH loads back-to-back (independent addresses).
        f4_t xv[BATCH];
        #pragma unroll
        for (int j = 0; j < BATCH; ++j)
            xv[j] = x4[base + (long)(sc + j) * H4_];

        // Phase 2: compute + nontemporal store (y is never re-read; keep it
        // out of L2/L3 so x stays cache-resident).
        #pragma unroll
        for (int j = 0; j < BATCH; ++j) {
            const f4_t a3 = (j >= 3) ? xv[j-3] : (j == 0 ? xm3 : (j == 1 ? xm2 : xm1));
            const f4_t a2 = (j >= 2) ? xv[j-2] : (j == 0 ? xm2 : xm1);
            const f4_t a1 = (j >= 1) ? xv[j-1] : xm1;
            const f4_t a0 = xv[j];
            const float m = mask[b * S_ + sc + j];

            f4_t o;
            o.x = fmaf(a3.x, w0.x, fmaf(a2.x, w0.y, fmaf(a1.x, w0.z, a0.x * w0.w)));
            o.y = fmaf(a3.y, w1.x, fmaf(a2.y, w1.y, fmaf(a1.y, w1.z, a0.y * w1.w)));
            o.z = fmaf(a3.z, w2.x, fmaf(a2.z, w2.y, fmaf(a1.z, w2.z, a0.z * w2.w)));
            o.w = fmaf(a3.w, w3.x, fmaf(a2.w, w3.y, fmaf(a1.w, w3.z, a0.w * w3.w)));
            o *= m;

            __builtin_nontemporal_store(o, &y4[base + (long)(sc + j) * H4_]);
        }

        xm3 = xv[BATCH - 3];
        xm2 = xv[BATCH - 2];
        xm1 = xv[BATCH - 1];
    }
}

extern "C" void kernel_launch(void* const* d_in, const int* in_sizes, int n_in,
                              void* d_out, int out_size, void* d_ws, size_t ws_size,
                              hipStream_t stream) {
    const float* x    = (const float*)d_in[0];   // hidden_states [B,S,H]
    const float* w    = (const float*)d_in[1];   // weight [H,K]
    const float* mask = (const float*)d_in[2];   // attention_mask_2d [B,S]
    float* y = (float*)d_out;

    dim3 grid(H4_ / TPB, S_ / T_, B_);           // (2, 128, 4) = 1024 blocks
    budgie_dwconv1d_kernel<<<grid, TPB, 0, stream>>>(x, w, mask, y);
}